// Round 9
// baseline (112.544 us; speedup 1.0000x reference)
//
#include <hip/hip_runtime.h>
#include <cstddef>

#define HDIM 2048
#define NE 64
#define TOPK 4
#define BM2 32

// ---------- transpose+scale pre-pass: wt[k][e] = w[e][k] * scale[k] ----------
__global__ __launch_bounds__(256) void transpose_w_kernel(
    const float* __restrict__ w, const float* __restrict__ scale,
    float* __restrict__ wt)
{
    __shared__ float Wl[64][65];
    const int tid = threadIdx.x;
    const int k0 = blockIdx.x * 64;          // grid = HDIM/64 = 32
    #pragma unroll
    for (int q = 0; q < 4; q++) {
        int f = tid + 256 * q;
        int e = f >> 4;
        int k4 = (f & 15) * 4;
        float4 v = *(const float4*)(w + (size_t)e * HDIM + k0 + k4);
        Wl[e][k4 + 0] = v.x; Wl[e][k4 + 1] = v.y;
        Wl[e][k4 + 2] = v.z; Wl[e][k4 + 3] = v.w;
    }
    __syncthreads();
    #pragma unroll
    for (int q = 0; q < 4; q++) {
        int f = tid + 256 * q;
        int k = f >> 4;
        int e4 = (f & 15) * 4;
        float s = scale[k0 + k];
        float4 v;
        v.x = Wl[e4 + 0][k] * s; v.y = Wl[e4 + 1][k] * s;
        v.z = Wl[e4 + 2][k] * s; v.w = Wl[e4 + 3][k] * s;
        *(float4*)(wt + (size_t)(k0 + k) * NE + e4) = v;
    }
}

// ---------- GEMM: wave-autonomous, per-wave DOUBLE-BUFFERED LDS panes ----------
// 512 thr = 8 waves, grid 256 -> 1 block/CU. No __syncthreads, and now no
// lgkmcnt drain either: chunk c+1 goes to the other pane while chunk c is
// read (same-wave DS ops complete in order). Globals loaded 2 chunks ahead.
template<int KS>
__global__ __launch_bounds__(512, 2) void gemm9_kernel(
    const float* __restrict__ x, const float* __restrict__ wt,
    float* __restrict__ sp0,     // partial scores ks=0 (probs region)
    float* __restrict__ spws,    // partial scores ks=1..KS-1
    float* __restrict__ sq,      // [KS][tokens] partial ssq
    int tokens)
{
    constexpr int KR = HDIM / KS;        // 256 @ KS=8
    constexpr int NCH = KR / 8;          // 32 chunks of 8 k
    __shared__ float AB[8][2][2][64][12];  // [wave][buf][A|B][row][12] = 96 KB

    const int tid = threadIdx.x;
    const int w = tid >> 6;
    const int l = tid & 63;
    const int ks = blockIdx.x & (KS - 1);
    const int tile = blockIdx.x / KS;
    const int tokw0 = tile * 512 + w * 64;
    const int k0 = ks * KR;

    float (*As0)[12] = AB[w][0][0];
    float (*Bs0)[12] = AB[w][0][1];
    float (*As1)[12] = AB[w][1][0];
    float (*Bs1)[12] = AB[w][1][1];

    const int tr = l & 7;                // token-octet (compute)
    const int ec = l >> 3;               // expert-octet (compute)

    // A staging: lane -> (tokens atok, atok+32; k-half ah)
    const int atok = l >> 1;
    const int ah = l & 1;
    const int aswz = ah ^ ((l >> 4) & 1);
    const float* xa0 = x + (size_t)(tokw0 + atok) * HDIM + k0 + 4 * ah;
    const float* xa1 = xa0 + (size_t)32 * HDIM;

    // B staging: lane -> (k-row bk, expert-octet bm)
    const int bk = l >> 3;
    const int bm = l & 7;
    const float* wb = wt + (size_t)(k0 + bk) * NE + 8 * bm;

    float acc[8][8];
    #pragma unroll
    for (int i = 0; i < 8; i++)
        #pragma unroll
        for (int j = 0; j < 8; j++) acc[i][j] = 0.f;
    float ssq0 = 0.f, ssq1 = 0.f;

    float4 ra0, ra1, rb0, rb1;           // reg set R (even chunks after prologue)
    float4 sa0, sa1, sb0, sb1;           // reg set S (odd chunks)

#define LOADR(c) { ra0 = *(const float4*)(xa0 + (c) * 8); \
                   ra1 = *(const float4*)(xa1 + (c) * 8); \
                   rb0 = *(const float4*)(wb + (size_t)(c) * 8 * NE); \
                   rb1 = *(const float4*)(wb + (size_t)(c) * 8 * NE + 4); }
#define LOADS(c) { sa0 = *(const float4*)(xa0 + (c) * 8); \
                   sa1 = *(const float4*)(xa1 + (c) * 8); \
                   sb0 = *(const float4*)(wb + (size_t)(c) * 8 * NE); \
                   sb1 = *(const float4*)(wb + (size_t)(c) * 8 * NE + 4); }
#define STOREP(As, Bs, a0, a1, b0, b1) { \
        *(float4*)&As[atok][4 * aswz] = a0; \
        *(float4*)&As[32 + atok][4 * aswz] = a1; \
        ssq0 += a0.x*a0.x + a0.y*a0.y + a0.z*a0.z + a0.w*a0.w; \
        ssq1 += a1.x*a1.x + a1.y*a1.y + a1.z*a1.z + a1.w*a1.w; \
        { float pbf[8] = {b0.x, b0.y, b0.z, b0.w, b1.x, b1.y, b1.z, b1.w}; \
          _Pragma("unroll") \
          for (int s = 0; s < 8; ++s) Bs[8 * s + bm][bk] = pbf[s]; } }
#define COMPUTE(As, Bs) { \
        _Pragma("unroll") \
        for (int kq = 0; kq < 2; ++kq) { \
            float4 Ai[8]; \
            _Pragma("unroll") \
            for (int i = 0; i < 8; ++i) \
                Ai[i] = *(const float4*)&As[8 * i + tr][4 * (kq ^ (i & 1))]; \
            _Pragma("unroll") \
            for (int j = 0; j < 8; ++j) { \
                float4 Bf = *(const float4*)&Bs[8 * j + ec][4 * kq]; \
                _Pragma("unroll") \
                for (int i = 0; i < 8; ++i) { \
                    acc[i][j] = fmaf(Ai[i].x, Bf.x, acc[i][j]); \
                    acc[i][j] = fmaf(Ai[i].y, Bf.y, acc[i][j]); \
                    acc[i][j] = fmaf(Ai[i].z, Bf.z, acc[i][j]); \
                    acc[i][j] = fmaf(Ai[i].w, Bf.w, acc[i][j]); \
                } \
            } \
        } }

    LOADR(0);
    LOADS(1);
    STOREP(As0, Bs0, ra0, ra1, rb0, rb1);          // chunk 0 -> pane0

    for (int c = 0; c < NCH; c += 2) {
        // ---- chunk c on pane0 ----
        if (c + 2 < NCH) LOADR(c + 2);             // issue early: 2-chunk cover
        if (c + 1 < NCH) STOREP(As1, Bs1, sa0, sa1, sb0, sb1);  // chunk c+1 -> pane1
        COMPUTE(As0, Bs0);
        // ---- chunk c+1 on pane1 ----
        if (c + 1 < NCH) {
            if (c + 3 < NCH) LOADS(c + 3);
            if (c + 2 < NCH) STOREP(As0, Bs0, ra0, ra1, rb0, rb1);  // chunk c+2 -> pane0
            COMPUTE(As1, Bs1);
        }
    }
#undef LOADR
#undef LOADS
#undef STOREP
#undef COMPUTE

    // ssq: combine the two k-half lanes of each token (lanes 2t, 2t+1)
    ssq0 += __shfl_xor(ssq0, 1, 64);
    ssq1 += __shfl_xor(ssq1, 1, 64);
    if (ah == 0) {
        sq[(size_t)ks * tokens + tokw0 + atok] = ssq0;
        sq[(size_t)ks * tokens + tokw0 + 32 + atok] = ssq1;
    }

    float* sp = (ks == 0) ? sp0 : (spws + (size_t)(ks - 1) * tokens * NE);
    #pragma unroll
    for (int i = 0; i < 8; ++i) {
        size_t off = (size_t)(tokw0 + 8 * i + tr) * NE + 8 * ec;
        float4 v0 = {acc[i][0], acc[i][1], acc[i][2], acc[i][3]};
        float4 v1 = {acc[i][4], acc[i][5], acc[i][6], acc[i][7]};
        *(float4*)(sp + off) = v0;
        *(float4*)(sp + off + 4) = v1;
    }
}

// ---------- finisher: tree-sum KS partials, rmsnorm, softmax, top-4 ----------
template<int KS>
__global__ __launch_bounds__(256) void finish9_kernel(
    const float* __restrict__ sp0, const float* __restrict__ spws,
    const float* __restrict__ sq, const float* __restrict__ pes,
    float* __restrict__ probs, float* __restrict__ tkw, float* __restrict__ tki,
    int tokens)
{
    __shared__ float Sl[BM2 * 65];
    __shared__ float Pl[BM2 * 65];
    __shared__ float FN[BM2];
    __shared__ float RS[BM2];

    const int tid = threadIdx.x;
    const int tok0 = blockIdx.x * BM2;

    if (tid < BM2) {
        float q[KS];
        #pragma unroll
        for (int i = 0; i < KS; i++) q[i] = sq[(size_t)i * tokens + tok0 + tid];
        #pragma unroll
        for (int st = 1; st < KS; st <<= 1)
            #pragma unroll
            for (int i = 0; i < KS; i += 2 * st) q[i] += q[i + st];
        FN[tid] = rsqrtf(q[0] * (1.0f / HDIM) + 1e-6f) * 0.022097086912079612f;
    }
    __syncthreads();

    #pragma unroll
    for (int qq = 0; qq < 2; qq++) {
        int f = tid + 256 * qq;
        int m = f >> 4;
        int e4 = f & 15;
        float4 t[KS];
        t[0] = ((const float4*)sp0)[(size_t)(tok0 + m) * (NE / 4) + e4];
        #pragma unroll
        for (int i = 1; i < KS; i++)
            t[i] = ((const float4*)(spws + (size_t)(i - 1) * tokens * NE))
                       [(size_t)(tok0 + m) * (NE / 4) + e4];
        #pragma unroll
        for (int st = 1; st < KS; st <<= 1)
            #pragma unroll
            for (int i = 0; i < KS; i += 2 * st) {
                t[i].x += t[i + st].x; t[i].y += t[i + st].y;
                t[i].z += t[i + st].z; t[i].w += t[i + st].w;
            }
        float fn = FN[m];
        int base = m * 65 + e4 * 4;
        Sl[base + 0] = t[0].x * fn; Sl[base + 1] = t[0].y * fn;
        Sl[base + 2] = t[0].z * fn; Sl[base + 3] = t[0].w * fn;
    }
    __syncthreads();

    if (tid < BM2) {
        const int m = tid;
        float mx = -3.0e38f;
        for (int e = 0; e < NE; e++) mx = fmaxf(mx, Sl[m * 65 + e]);
        float sum = 0.f;
        for (int e = 0; e < NE; e++) {
            float p = __expf(Sl[m * 65 + e] - mx);
            Pl[m * 65 + e] = p;
            sum += p;
        }
        RS[m] = 1.0f / sum;
    }
    __syncthreads();

    #pragma unroll
    for (int qq = 0; qq < 2; qq++) {
        int f = tid + 256 * qq;
        int m = f >> 4;
        int e0 = (f & 15) * 4;
        float rs = RS[m];
        float4 pv;
        pv.x = Pl[m * 65 + e0 + 0] * rs;
        pv.y = Pl[m * 65 + e0 + 1] * rs;
        pv.z = Pl[m * 65 + e0 + 2] * rs;
        pv.w = Pl[m * 65 + e0 + 3] * rs;
        *(float4*)&probs[(size_t)(tok0 + m) * NE + e0] = pv;
    }

    if (tid < BM2) {                     // destructive top-4, lowest-index ties
        const int m = tid;
        float wv[TOPK]; int idx[TOPK];
        float wsum = 0.f;
        #pragma unroll
        for (int kk = 0; kk < TOPK; ++kk) {
            float best = -3.0e38f; int bi = 0;
            for (int e = 0; e < NE; e++) {
                float v = Sl[m * 65 + e];
                if (v > best) { best = v; bi = e; }
            }
            Sl[m * 65 + bi] = -3.4e38f;
            float p = Pl[m * 65 + bi];
            wv[kk] = p; idx[kk] = bi; wsum += p;
        }
        float inv = 1.0f / wsum;
        size_t ob = (size_t)(tok0 + m) * TOPK;
        #pragma unroll
        for (int kk = 0; kk < TOPK; kk++) {
            tkw[ob + kk] = wv[kk] * inv * pes[idx[kk]];
            tki[ob + kk] = (float)idx[kk];   // harness reads flat buffer as float32
        }
    }
}

extern "C" void kernel_launch(void* const* d_in, const int* in_sizes, int n_in,
                              void* d_out, int out_size, void* d_ws, size_t ws_size,
                              hipStream_t stream) {
    const float* x     = (const float*)d_in[0];
    const float* w     = (const float*)d_in[1];
    const float* scale = (const float*)d_in[2];
    const float* pes   = (const float*)d_in[3];
    const int tokens = in_sizes[0] / HDIM;      // 16384

    float* probs = (float*)d_out;
    float* tkw   = probs + (size_t)tokens * NE;
    float* tki   = tkw + (size_t)tokens * TOPK;

    const size_t wtN = (size_t)HDIM * NE;
    const size_t spN = (size_t)tokens * NE;
    const size_t need8 = (wtN + 7 * spN + (size_t)8 * tokens) * sizeof(float);
    const int KS = (ws_size >= need8) ? 8 : 4;

    float* wt   = (float*)d_ws;
    float* spws = wt + wtN;
    float* sq   = spws + (size_t)(KS - 1) * spN;
    float* sp0  = probs;                        // overwritten by finisher

    transpose_w_kernel<<<HDIM / 64, 256, 0, stream>>>(w, scale, wt);

    const int grid1 = (tokens / 512) * KS;      // 256 @ KS=8 -> 1 block/CU
    if (KS == 8)
        gemm9_kernel<8><<<grid1, 512, 0, stream>>>(x, wt, sp0, spws, sq, tokens);
    else
        gemm9_kernel<4><<<grid1, 512, 0, stream>>>(x, wt, sp0, spws, sq, tokens);

    const int grid2 = tokens / BM2;             // 512
    if (KS == 8)
        finish9_kernel<8><<<grid2, 256, 0, stream>>>(sp0, spws, sq, pes, probs, tkw, tki, tokens);
    else
        finish9_kernel<4><<<grid2, 256, 0, stream>>>(sp0, spws, sq, pes, probs, tkw, tki, tokens);
}